// Round 17
// baseline (2609.951 us; speedup 1.0000x reference)
//
#include <hip/hip_runtime.h>

typedef unsigned long long u64;
typedef unsigned int u32;

#define HF 32
#define TBL_BITS 22
#define TBL_SIZE (1u << TBL_BITS)
#define LP_ITERS 12
#define EMPTY_KEY 0xFFFFFFFFFFFFFFFFull
#define HSLOTS 256

// ---------------- CSR build (by dst) ----------------

__global__ void k_count(const int2* __restrict__ edges, int* __restrict__ cnt, int E) {
    int e = blockIdx.x * blockDim.x + threadIdx.x;
    if (e >= E) return;
    atomicAdd(&cnt[edges[e].y], 1);
}

__global__ void k_scan1(const int* __restrict__ cnt, int* __restrict__ row,
                        int* __restrict__ bsums, int N) {
    __shared__ int s[256];
    int tid = threadIdx.x;
    int i = blockIdx.x * 256 + tid;
    int v = (i < N) ? cnt[i] : 0;
    s[tid] = v;
    __syncthreads();
    for (int o = 1; o < 256; o <<= 1) {
        int t = (tid >= o) ? s[tid - o] : 0;
        __syncthreads();
        s[tid] += t;
        __syncthreads();
    }
    if (i < N) row[i] = s[tid] - v;
    if (tid == 255) bsums[blockIdx.x] = s[255];
}

__global__ void k_scan2(int* __restrict__ bsums, int nb) {
    __shared__ int s[1024];
    int tid = threadIdx.x;
    int v = (tid < nb) ? bsums[tid] : 0;
    s[tid] = v;
    __syncthreads();
    for (int o = 1; o < 1024; o <<= 1) {
        int t = (tid >= o) ? s[tid - o] : 0;
        __syncthreads();
        s[tid] += t;
        __syncthreads();
    }
    if (tid < nb) bsums[tid] = s[tid] - v;
}

__global__ void k_scan3(int* __restrict__ row, int* __restrict__ cursor,
                        const int* __restrict__ bsums, int N, int E) {
    int i = blockIdx.x * 256 + threadIdx.x;
    if (i < N) {
        int v = row[i] + bsums[blockIdx.x];
        row[i] = v;
        cursor[i] = v;
    }
    if (i == 0) row[N] = E;
}

// XCD-localized fill (round-16 win: kills 16x write amplification)
__global__ void k_fill(const int2* __restrict__ edges, int* __restrict__ cursor,
                       int* __restrict__ csr_src, int E, int N) {
    int xcd = blockIdx.x & 7;
    int nlo = (int)((long long)N * xcd >> 3);
    int nhi = (int)((long long)N * (xcd + 1) >> 3);
    int nblk = gridDim.x >> 3;
    int bslot = blockIdx.x >> 3;
    int stride = nblk * 256;
    for (int e = bslot * 256 + threadIdx.x; e < E; e += stride) {
        int2 ed = edges[e];
        if (ed.y >= nlo && ed.y < nhi) {
            int pos = atomicAdd(&cursor[ed.y], 1);
            csr_src[pos] = ed.x;
        }
    }
}

// ---------------- GCN 1 (h1 folded in) ----------------

__global__ void k_gather_x1(const int* __restrict__ row, const int* __restrict__ csr_src,
                            const float* __restrict__ x, const float* __restrict__ W1,
                            const float* __restrict__ b1, const float* __restrict__ wp,
                            float* __restrict__ x1, float* __restrict__ a_src,
                            float* __restrict__ a_dst, int* __restrict__ lab, int N) {
    __shared__ float w[96];
    __shared__ float wpl[64];
    __shared__ float b1l[32];
    int tid = threadIdx.x;
    if (tid < 96) w[tid] = W1[tid];
    if (tid < 64) wpl[tid] = wp[tid];
    if (tid < 32) b1l[tid] = b1[tid];
    __syncthreads();
    int t = blockIdx.x * blockDim.x + tid;
    int i = t >> 3, fg = t & 7;
    if (i >= N) return;
    int f = fg * 4;
    float wa0 = w[f + 0], wa1 = w[f + 1], wa2 = w[f + 2], wa3 = w[f + 3];
    float wb0 = w[32 + f + 0], wb1 = w[32 + f + 1], wb2 = w[32 + f + 2], wb3 = w[32 + f + 3];
    float wc0 = w[64 + f + 0], wc1 = w[64 + f + 1], wc2 = w[64 + f + 2], wc3 = w[64 + f + 3];
    int r0 = row[i], r1 = row[i + 1];
    float disI = rsqrtf((float)(r1 - r0) + 1.0f);
    float xi0 = x[3 * i + 0], xi1 = x[3 * i + 1], xi2 = x[3 * i + 2];
    float4 acc;
    acc.x = (xi0 * wa0 + xi1 * wb0 + xi2 * wc0) * disI;
    acc.y = (xi0 * wa1 + xi1 * wb1 + xi2 * wc1) * disI;
    acc.z = (xi0 * wa2 + xi1 * wb2 + xi2 * wc2) * disI;
    acc.w = (xi0 * wa3 + xi1 * wb3 + xi2 * wc3) * disI;
    for (int j = r0; j < r1; j++) {
        int s = csr_src[j];
        float s0 = x[3 * s + 0], s1 = x[3 * s + 1], s2 = x[3 * s + 2];
        int sr0 = row[s], sr1 = row[s + 1];
        float disS = rsqrtf((float)(sr1 - sr0) + 1.0f);
        acc.x += (s0 * wa0 + s1 * wb0 + s2 * wc0) * disS;
        acc.y += (s0 * wa1 + s1 * wb1 + s2 * wc1) * disS;
        acc.z += (s0 * wa2 + s1 * wb2 + s2 * wc2) * disS;
        acc.w += (s0 * wa3 + s1 * wb3 + s2 * wc3) * disS;
    }
    float4 r;
    r.x = fmaxf(disI * acc.x + b1l[f + 0], 0.0f);
    r.y = fmaxf(disI * acc.y + b1l[f + 1], 0.0f);
    r.z = fmaxf(disI * acc.z + b1l[f + 2], 0.0f);
    r.w = fmaxf(disI * acc.w + b1l[f + 3], 0.0f);
    ((float4*)x1)[i * 8 + fg] = r;
    float ps = r.x * wpl[f + 0] + r.y * wpl[f + 1] + r.z * wpl[f + 2] + r.w * wpl[f + 3];
    float pd = r.x * wpl[32 + f + 0] + r.y * wpl[32 + f + 1] + r.z * wpl[32 + f + 2] + r.w * wpl[32 + f + 3];
#pragma unroll
    for (int o = 4; o; o >>= 1) {
        ps += __shfl_xor(ps, o);
        pd += __shfl_xor(pd, o);
    }
    if (fg == 0) {
        a_src[i] = ps;
        a_dst[i] = pd;
        lab[i] = i;
    }
}

// ---------------- edge selection + seed relax (LP iteration "-1" for free) ----------------

__global__ void k_select(const int2* __restrict__ edges, const float* __restrict__ a_src,
                         const float* __restrict__ a_dst, const float* __restrict__ bp,
                         long long* __restrict__ seluv, float* __restrict__ selsc,
                         int* __restrict__ selcnt, int* __restrict__ lab, int E) {
    __shared__ int wsum[4];
    __shared__ int sbase;
    int tid = threadIdx.x;
    int e = blockIdx.x * 256 + tid;
    bool sel = false;
    long long pk = 0;
    float score = 0.0f;
    if (e < E) {
        int2 ed = edges[e];
        float z = a_src[ed.x] + a_dst[ed.y] + bp[0];
        score = 1.0f / (1.0f + expf(-z));
        if (score > 0.5f) {
            sel = true;
            pk = ((long long)ed.x << 32) | (u32)ed.y;
            int lu = lab[ed.x], lv = lab[ed.y];
            if (lu < lv) atomicMin(&lab[ed.y], lu);        // posted seed hook
            else if (lv < lu) atomicMin(&lab[ed.x], lv);
        }
    }
    u64 m = __ballot(sel);
    int wid = tid >> 6, lane = tid & 63;
    if (lane == 0) wsum[wid] = __popcll(m);
    __syncthreads();
    if (tid == 0) {
        int tot = wsum[0] + wsum[1] + wsum[2] + wsum[3];
        sbase = tot ? atomicAdd(selcnt, tot) : 0;
    }
    __syncthreads();
    if (sel) {
        int woff = 0;
        for (int k = 0; k < wid; k++) woff += wsum[k];
        int rank = __popcll(m & ((1ull << lane) - 1ull));
        int pos = sbase + woff + rank;
        seluv[pos] = pk;
        selsc[pos] = score;
    }
}

// ---------------- CC via frontier-shrinking min-label propagation ----------------
// An edge observed with lu==lv has a common label-ancestor -> same tree forever
// (trees only merge), so it is dropped from the frontier. The flags gate stops
// only after a full no-change pass: then labels are fully compressed and all
// frontier edges equal -> dropped intra-tree edges are satisfied automatically
// -> exact component-min fixed point. Frontier shrinks geometrically, killing
// the round-16 signature (每 active iteration re-reads the full 1M-edge list).

__global__ void k_lp(const long long* __restrict__ frsrc, const int* __restrict__ pcsrc,
                     long long* __restrict__ frdst, int* __restrict__ pcdst,
                     int* __restrict__ lab, int* __restrict__ flags, int t, int N) {
    if (t > 0 && flags[t - 1] == 0) return;
    __shared__ int wsum[4];
    __shared__ int sbase;
    int n = *pcsrc;
    int tid = threadIdx.x;
    int wid = tid >> 6, lane = tid & 63;
    int ch = 0;
    for (int base = blockIdx.x * 256; base < n; base += gridDim.x * 256) {
        int idx = base + tid;
        bool keep = false;
        long long pk = 0;
        if (idx < n) {
            pk = frsrc[idx];
            int u = (int)(pk >> 32), v = (int)(u32)pk;
            int lu = lab[u], lv = lab[v];
            if (lu < lv) { atomicMin(&lab[v], lu); keep = true; ch = 1; }
            else if (lv < lu) { atomicMin(&lab[u], lv); keep = true; ch = 1; }
        }
        u64 m = __ballot(keep);
        if (lane == 0) wsum[wid] = __popcll(m);
        __syncthreads();
        if (tid == 0) {
            int tot = wsum[0] + wsum[1] + wsum[2] + wsum[3];
            sbase = tot ? atomicAdd(pcdst, tot) : 0;
        }
        __syncthreads();
        if (keep) {
            int woff = 0;
            for (int k = 0; k < wid; k++) woff += wsum[k];
            int rank = __popcll(m & ((1ull << lane) - 1ull));
            frdst[sbase + woff + rank] = pk;
        }
        __syncthreads();
    }
    // double pointer-jump over all nodes (verifies full compression at fixpoint)
    int tid0 = blockIdx.x * blockDim.x + tid;
    int stride = gridDim.x * blockDim.x;
    for (int i = tid0; i < N; i += stride) {
        int l = lab[i];
        int m = lab[l];
        int m2 = lab[m];
        if (m2 < l) { atomicMin(&lab[i], m2); ch = 1; }
    }
    if (__ballot(ch) && lane == 0) flags[t] = 1;
}

// ---------------- component stats (LDS-hash privatized histogram) ----------------

__global__ void k_cnt_ssum(const long long* __restrict__ seluv, const float* __restrict__ selsc,
                           const int* __restrict__ pcnt, const int* __restrict__ lab,
                           float* __restrict__ cnt, float* __restrict__ ssum) {
    __shared__ int hkey[HSLOTS];
    __shared__ float hcnt[HSLOTS];
    __shared__ float hsum[HSLOTS];
    int tid = threadIdx.x;
    for (int k = tid; k < HSLOTS; k += 256) {
        hkey[k] = -1;
        hcnt[k] = 0.0f;
        hsum[k] = 0.0f;
    }
    __syncthreads();
    int n = *pcnt;
    for (int base = blockIdx.x * blockDim.x; base < n; base += gridDim.x * blockDim.x) {
        int idx = base + tid;
        bool valid = idx < n;
        int g = -1;
        float score = 0.0f;
        if (valid) {
            long long pk = seluv[idx];
            int s = (int)(pk >> 32);
            score = selsc[idx];
            g = lab[s];
        }
        u64 m = __ballot(valid);
        while (m) {
            int leader = __ffsll(m) - 1;
            int g0 = __shfl(g, leader);
            bool match = valid && (g == g0);
            float c = match ? 1.0f : 0.0f;
            float sv = match ? score : 0.0f;
#pragma unroll
            for (int o = 32; o; o >>= 1) {
                c += __shfl_xor(c, o);
                sv += __shfl_xor(sv, o);
            }
            if ((int)(tid & 63) == leader) {
                u32 h = ((u32)g0 * 0x9E3779B9u) >> 24;
                bool done = false;
                for (int probe = 0; probe < 16; probe++) {
                    int k = (int)((h + probe) & (HSLOTS - 1));
                    int prev = atomicCAS(&hkey[k], -1, g0);
                    if (prev == -1 || prev == g0) {
                        atomicAdd(&hcnt[k], c);
                        atomicAdd(&hsum[k], sv);
                        done = true;
                        break;
                    }
                }
                if (!done) {
                    atomicAdd(&cnt[g0], c);
                    atomicAdd(&ssum[g0], sv);
                }
            }
            m &= ~__ballot(match);
        }
    }
    __syncthreads();
    for (int k = tid; k < HSLOTS; k += 256) {
        int g = hkey[k];
        if (g >= 0) {
            atomicAdd(&cnt[g], hcnt[k]);
            atomicAdd(&ssum[g], hsum[k]);
        }
    }
}

// load-gated same-address atomicMax (broadcast read; skips once settled)
__global__ void k_findgl(const float* __restrict__ cnt, u64* __restrict__ glpack, int N) {
    int i = blockIdx.x * blockDim.x + threadIdx.x;
    u64 v = 0;
    if (i < N) v = ((u64)__float_as_uint(cnt[i]) << 32) | (u32)i;
#pragma unroll
    for (int o = 32; o; o >>= 1) {
        u64 ov = __shfl_xor(v, o);
        v = v > ov ? v : ov;
    }
    if ((int)(threadIdx.x & 63) == 0) {
        if (*glpack < v) atomicMax(glpack, v);
    }
}

// nx[lab[i]] += x1[i], giant row via LDS per block
__global__ void k_nx_scatter(const float* __restrict__ x1, const int* __restrict__ lab,
                             const u64* __restrict__ glpack, float* __restrict__ nx, int N) {
    __shared__ float ls[HF];
    int tid = threadIdx.x;
    if (tid < HF) ls[tid] = 0.0f;
    __syncthreads();
    int gl = (int)(u32)(*glpack);
    int t = blockIdx.x * blockDim.x + tid;
    int i = t >> 3, fg = t & 7;
    if (i < N) {
        int l = lab[i];
        float4 v = ((const float4*)x1)[i * 8 + fg];
        if (l == gl) {
            atomicAdd(&ls[fg * 4 + 0], v.x);
            atomicAdd(&ls[fg * 4 + 1], v.y);
            atomicAdd(&ls[fg * 4 + 2], v.z);
            atomicAdd(&ls[fg * 4 + 3], v.w);
        } else {
            float* d = &nx[l * HF + fg * 4];
            atomicAdd(d + 0, v.x);
            atomicAdd(d + 1, v.y);
            atomicAdd(d + 2, v.z);
            atomicAdd(d + 3, v.w);
        }
    }
    __syncthreads();
    if (tid < HF) {
        float s = ls[tid];
        if (s != 0.0f) atomicAdd(&nx[gl * HF + tid], s);
    }
}

// ---------------- coarse graph ----------------

__global__ void k_hash_insert(const int2* __restrict__ edges, const int* __restrict__ lab,
                              u64* __restrict__ htab, float* __restrict__ deg3, int E) {
    int e = blockIdx.x * blockDim.x + threadIdx.x;
    if (e >= E) return;
    int2 ed = edges[e];
    int ru = lab[ed.x];
    int rv = lab[ed.y];
    if (ru == rv) return;
    u64 key = ((u64)(u32)ru << 32) | (u32)rv;
    u32 slot = (u32)((key * 0x9E3779B97F4A7C15ull) >> (64 - TBL_BITS));
    bool won = false;
    for (;;) {
        u64 cur = htab[slot];
        if (cur == key) break;
        if (cur == EMPTY_KEY) {
            u64 prev = atomicCAS(&htab[slot], EMPTY_KEY, key);
            if (prev == EMPTY_KEY) { won = true; break; }
            if (prev == key) break;
        }
        slot = (slot + 1) & (TBL_SIZE - 1);
    }
    if (won) atomicAdd(&deg3[rv], 1.0f);
}

// per rep node: cscore, dis3, hs3 = (nx*cscore @ W3) * dis3
__global__ void k_h3(const float* __restrict__ nx, const float* __restrict__ cnt,
                     const float* __restrict__ ssum, const float* __restrict__ deg3,
                     const int* __restrict__ lab, const float* __restrict__ W3,
                     float* __restrict__ hs3, float* __restrict__ dis3, int N) {
    __shared__ float w[HF * HF];
    int tid = threadIdx.x;
    for (int k = tid; k < HF * HF; k += blockDim.x) w[k] = W3[k];
    __syncthreads();
    int i = blockIdx.x * blockDim.x + tid;
    if (i >= N) return;
    if (lab[i] != i) {
        dis3[i] = 0.0f;
        return;
    }
    float cn = cnt[i];
    float c = cn > 0.0f ? ssum[i] / fmaxf(cn, 1.0f) : 1.0f;
    float d3 = 1.0f / sqrtf(deg3[i] + 1.0f);
    dis3[i] = d3;
    float scale = c * d3;
    float r[HF];
#pragma unroll
    for (int f = 0; f < HF; f++) r[f] = 0.0f;
    for (int k = 0; k < HF; k++) {
        float xv = nx[i * HF + k];
#pragma unroll
        for (int f = 0; f < HF; f++) r[f] += xv * w[k * HF + f];
    }
#pragma unroll
    for (int f = 0; f < HF; f++) hs3[i * HF + f] = r[f] * scale;
}

// acc3[b] += hs3[a] for each unique coarse edge (a,b); giant row via LDS
__global__ void k_hash_scatter(const u64* __restrict__ htab, const float* __restrict__ hs3,
                               float* __restrict__ acc3, const u64* __restrict__ glpack) {
    __shared__ float ls[HF];
    int tid = threadIdx.x;
    if (tid < HF) ls[tid] = 0.0f;
    __syncthreads();
    int gl = (int)(u32)(*glpack);
    int t = blockIdx.x * blockDim.x + tid;
    u32 slot = (u32)(t >> 3);
    int fg = t & 7;
    u64 key = htab[slot];
    if (key != EMPTY_KEY) {
        int a = (int)(key >> 32), b = (int)(u32)key;
        float4 v = ((const float4*)hs3)[a * 8 + fg];
        if (b == gl) {
            atomicAdd(&ls[fg * 4 + 0], v.x);
            atomicAdd(&ls[fg * 4 + 1], v.y);
            atomicAdd(&ls[fg * 4 + 2], v.z);
            atomicAdd(&ls[fg * 4 + 3], v.w);
        } else {
            float* d = &acc3[b * HF + fg * 4];
            atomicAdd(d + 0, v.x);
            atomicAdd(d + 1, v.y);
            atomicAdd(d + 2, v.z);
            atomicAdd(d + 3, v.w);
        }
    }
    __syncthreads();
    if (tid < HF) {
        float s = ls[tid];
        if (s != 0.0f) atomicAdd(&acc3[gl * HF + tid], s);
    }
}

// x3 = relu(dis3*(acc3+hs3)+b3) at reps; pool into gs/gc by batch
__global__ void k_final(const float* __restrict__ acc3, const float* __restrict__ hs3,
                        const float* __restrict__ dis3, const int* __restrict__ lab,
                        const int* __restrict__ batch, const float* __restrict__ b3,
                        float* __restrict__ gs, float* __restrict__ gc, int N) {
    int t = blockIdx.x * blockDim.x + threadIdx.x;
    int i = t >> 3, fg = t & 7;
    if (i >= N) return;
    if (lab[i] != i) return;
    float d3 = dis3[i];
    float4 a = ((const float4*)acc3)[i * 8 + fg];
    float4 h = ((const float4*)hs3)[i * 8 + fg];
    int f = fg * 4;
    float4 x3;
    x3.x = fmaxf(d3 * (a.x + h.x) + b3[f + 0], 0.0f);
    x3.y = fmaxf(d3 * (a.y + h.y) + b3[f + 1], 0.0f);
    x3.z = fmaxf(d3 * (a.z + h.z) + b3[f + 2], 0.0f);
    x3.w = fmaxf(d3 * (a.w + h.w) + b3[f + 3], 0.0f);
    int b = batch[i];
    float* g = &gs[b * HF + f];
    atomicAdd(g + 0, x3.x);
    atomicAdd(g + 1, x3.y);
    atomicAdd(g + 2, x3.z);
    atomicAdd(g + 3, x3.w);
    if (fg == 0) atomicAdd(&gc[b], 1.0f);
}

__global__ void k_out(const float* __restrict__ gs, const float* __restrict__ gc,
                      const float* __restrict__ Wf, const float* __restrict__ bf,
                      float* __restrict__ out, int B) {
    int b = threadIdx.x + blockIdx.x * blockDim.x;
    if (b >= B) return;
    float inv = 1.0f / fmaxf(gc[b], 1.0f);
    float z = 0.0f;
#pragma unroll
    for (int f = 0; f < HF; f++) z += gs[b * HF + f] * inv * Wf[f];
    z += bf[0];
    out[b] = 1.0f / (1.0f + expf(-z));
}

// ---------------- host ----------------

static inline size_t align256(size_t x) { return (x + 255) & ~(size_t)255; }

extern "C" void kernel_launch(void* const* d_in, const int* in_sizes, int n_in,
                              void* d_out, int out_size, void* d_ws, size_t ws_size,
                              hipStream_t stream) {
    const float* x = (const float*)d_in[0];
    const int2* edges = (const int2*)d_in[1];
    const int* batch = (const int*)d_in[2];
    const float* W1 = (const float*)d_in[3];
    const float* b1 = (const float*)d_in[4];
    const float* wp = (const float*)d_in[5];
    const float* bp = (const float*)d_in[6];
    const float* W3 = (const float*)d_in[7];
    const float* b3 = (const float*)d_in[8];
    const float* Wf = (const float*)d_in[9];
    const float* bf = (const float*)d_in[10];
    float* outp = (float*)d_out;

    const int N = in_sizes[2];
    const int E = in_sizes[1] / 2;
    const int B = out_size;

    char* p = (char*)d_ws;
    size_t off = 0;
    auto alloc = [&](size_t bytes) -> void* {
        void* r = p + off;
        off = align256(off + bytes);
        return r;
    };
    float* f0 = (float*)alloc((size_t)N * HF * 4);   // nx -> acc3
    float* f1 = (float*)alloc((size_t)N * HF * 4);   // x1 -> hs3
    int* row = (int*)alloc((size_t)(N + 1) * 4);
    int* cursor = (int*)alloc((size_t)N * 4);
    int* bsums = (int*)alloc(4096);
    int* csr_src = (int*)alloc((size_t)E * 4);
    float* a_src = (float*)alloc((size_t)N * 4);
    float* a_dst = (float*)alloc((size_t)N * 4);
    int* lab = (int*)alloc((size_t)N * 4);
    float* cnt = (float*)alloc((size_t)N * 4);
    float* ssum = (float*)alloc((size_t)N * 4);
    float* deg3 = (float*)alloc((size_t)N * 4);
    float* dis3 = (float*)alloc((size_t)N * 4);
    long long* seluv = (long long*)alloc((size_t)E * 8);
    float* selsc = (float*)alloc((size_t)E * 4);
    long long* frB = (long long*)alloc((size_t)E * 8);
    long long* frC = (long long*)alloc((size_t)E * 8);
    int* fc = (int*)alloc(8);
    int* selcnt = (int*)alloc(4);
    int* flags = (int*)alloc(LP_ITERS * 4);
    u64* glpack = (u64*)alloc(8);
    float* gs = (float*)alloc((size_t)B * HF * 4);
    float* gc = (float*)alloc((size_t)B * 4);
    u64* htab = (u64*)alloc((size_t)TBL_SIZE * 8);
    (void)ws_size; (void)n_in;

    const int nb_e = (E + 255) / 256;
    const int nb_n8 = (int)(((size_t)N * 8 + 255) / 256);
    const int nb_n = (N + 255) / 256;
    const int nb_tbl8 = (int)(((size_t)TBL_SIZE * 8) / 256);

    hipMemsetAsync(cursor, 0, (size_t)N * 4, stream);
    hipMemsetAsync(cnt, 0, (size_t)N * 4, stream);
    hipMemsetAsync(ssum, 0, (size_t)N * 4, stream);
    hipMemsetAsync(selcnt, 0, 4, stream);
    hipMemsetAsync(deg3, 0, (size_t)N * 4, stream);
    hipMemsetAsync(flags, 0, LP_ITERS * 4, stream);
    hipMemsetAsync(glpack, 0, 8, stream);
    hipMemsetAsync(gs, 0, (size_t)B * HF * 4, stream);
    hipMemsetAsync(gc, 0, (size_t)B * 4, stream);
    hipMemsetAsync(htab, 0xFF, (size_t)TBL_SIZE * 8, stream);

    // CSR build (sorted by dst); fill is XCD-localized
    k_count<<<nb_e, 256, 0, stream>>>(edges, cursor, E);
    k_scan1<<<nb_n, 256, 0, stream>>>(cursor, row, bsums, N);
    k_scan2<<<1, 1024, 0, stream>>>(bsums, nb_n);
    k_scan3<<<nb_n, 256, 0, stream>>>(row, cursor, bsums, N, E);
    k_fill<<<2048, 256, 0, stream>>>(edges, cursor, csr_src, E, N);

    // GCN1 fused (h1 on the fly); lab init
    k_gather_x1<<<nb_n8, 256, 0, stream>>>(row, csr_src, x, W1, b1, wp, f1, a_src, a_dst, lab, N);

    // CC: select (+seed relax), then frontier-shrinking label propagation
    k_select<<<nb_e, 256, 0, stream>>>(edges, a_src, a_dst, bp, seluv, selsc, selcnt, lab, E);
    for (int t = 0; t < LP_ITERS; t++) {
        const long long* src = (t == 0) ? seluv : ((t & 1) ? frB : frC);
        const int* srcc = (t == 0) ? selcnt : &fc[(t + 1) & 1];
        long long* dst = (t & 1) ? frC : frB;
        int* dstc = &fc[t & 1];
        hipMemsetAsync(dstc, 0, 4, stream);
        k_lp<<<2048, 256, 0, stream>>>(src, srcc, dst, dstc, lab, flags, t, N);
    }

    // component stats
    k_cnt_ssum<<<1024, 256, 0, stream>>>(seluv, selsc, selcnt, lab, cnt, ssum);
    k_findgl<<<nb_n, 256, 0, stream>>>(cnt, glpack, N);
    hipMemsetAsync(f0, 0, (size_t)N * HF * 4, stream);
    k_nx_scatter<<<nb_n8, 256, 0, stream>>>(f1, lab, glpack, f0, N);

    // coarse graph
    k_hash_insert<<<nb_e, 256, 0, stream>>>(edges, lab, htab, deg3, E);
    k_h3<<<nb_n, 256, 0, stream>>>(f0, cnt, ssum, deg3, lab, W3, f1, dis3, N);
    hipMemsetAsync(f0, 0, (size_t)N * HF * 4, stream);
    k_hash_scatter<<<nb_tbl8, 256, 0, stream>>>(htab, f1, f0, glpack);
    k_final<<<nb_n8, 256, 0, stream>>>(f0, f1, dis3, lab, batch, b3, gs, gc, N);
    k_out<<<1, 128, 0, stream>>>(gs, gc, Wf, bf, outp, B);
}

// Round 18
// 925.662 us; speedup vs baseline: 2.8195x; 2.8195x over previous
//
#include <hip/hip_runtime.h>

typedef unsigned long long u64;
typedef unsigned int u32;

#define HF 32
#define TBL_BITS 22
#define TBL_SIZE (1u << TBL_BITS)
#define LP_ITERS 12
#define EMPTY_KEY 0xFFFFFFFFFFFFFFFFull
#define HSLOTS 256

// ---------------- CSR build (by dst) ----------------

__global__ void k_count(const int2* __restrict__ edges, int* __restrict__ cnt, int E) {
    int e = blockIdx.x * blockDim.x + threadIdx.x;
    if (e >= E) return;
    atomicAdd(&cnt[edges[e].y], 1);
}

__global__ void k_scan1(const int* __restrict__ cnt, int* __restrict__ row,
                        int* __restrict__ bsums, int N) {
    __shared__ int s[256];
    int tid = threadIdx.x;
    int i = blockIdx.x * 256 + tid;
    int v = (i < N) ? cnt[i] : 0;
    s[tid] = v;
    __syncthreads();
    for (int o = 1; o < 256; o <<= 1) {
        int t = (tid >= o) ? s[tid - o] : 0;
        __syncthreads();
        s[tid] += t;
        __syncthreads();
    }
    if (i < N) row[i] = s[tid] - v;
    if (tid == 255) bsums[blockIdx.x] = s[255];
}

__global__ void k_scan2(int* __restrict__ bsums, int nb) {
    __shared__ int s[1024];
    int tid = threadIdx.x;
    int v = (tid < nb) ? bsums[tid] : 0;
    s[tid] = v;
    __syncthreads();
    for (int o = 1; o < 1024; o <<= 1) {
        int t = (tid >= o) ? s[tid - o] : 0;
        __syncthreads();
        s[tid] += t;
        __syncthreads();
    }
    if (tid < nb) bsums[tid] = s[tid] - v;
}

__global__ void k_scan3(int* __restrict__ row, int* __restrict__ cursor,
                        const int* __restrict__ bsums, int N, int E) {
    int i = blockIdx.x * 256 + threadIdx.x;
    if (i < N) {
        int v = row[i] + bsums[blockIdx.x];
        row[i] = v;
        cursor[i] = v;
    }
    if (i == 0) row[N] = E;
}

// XCD-localized fill (round-16 win: kills 16x write amplification)
__global__ void k_fill(const int2* __restrict__ edges, int* __restrict__ cursor,
                       int* __restrict__ csr_src, int E, int N) {
    int xcd = blockIdx.x & 7;
    int nlo = (int)((long long)N * xcd >> 3);
    int nhi = (int)((long long)N * (xcd + 1) >> 3);
    int nblk = gridDim.x >> 3;
    int bslot = blockIdx.x >> 3;
    int stride = nblk * 256;
    for (int e = bslot * 256 + threadIdx.x; e < E; e += stride) {
        int2 ed = edges[e];
        if (ed.y >= nlo && ed.y < nhi) {
            int pos = atomicAdd(&cursor[ed.y], 1);
            csr_src[pos] = ed.x;
        }
    }
}

// ---------------- GCN 1 (h1 folded in) ----------------

__global__ void k_gather_x1(const int* __restrict__ row, const int* __restrict__ csr_src,
                            const float* __restrict__ x, const float* __restrict__ W1,
                            const float* __restrict__ b1, const float* __restrict__ wp,
                            float* __restrict__ x1, float* __restrict__ a_src,
                            float* __restrict__ a_dst, int* __restrict__ lab, int N) {
    __shared__ float w[96];
    __shared__ float wpl[64];
    __shared__ float b1l[32];
    int tid = threadIdx.x;
    if (tid < 96) w[tid] = W1[tid];
    if (tid < 64) wpl[tid] = wp[tid];
    if (tid < 32) b1l[tid] = b1[tid];
    __syncthreads();
    int t = blockIdx.x * blockDim.x + tid;
    int i = t >> 3, fg = t & 7;
    if (i >= N) return;
    int f = fg * 4;
    float wa0 = w[f + 0], wa1 = w[f + 1], wa2 = w[f + 2], wa3 = w[f + 3];
    float wb0 = w[32 + f + 0], wb1 = w[32 + f + 1], wb2 = w[32 + f + 2], wb3 = w[32 + f + 3];
    float wc0 = w[64 + f + 0], wc1 = w[64 + f + 1], wc2 = w[64 + f + 2], wc3 = w[64 + f + 3];
    int r0 = row[i], r1 = row[i + 1];
    float disI = rsqrtf((float)(r1 - r0) + 1.0f);
    float xi0 = x[3 * i + 0], xi1 = x[3 * i + 1], xi2 = x[3 * i + 2];
    float4 acc;
    acc.x = (xi0 * wa0 + xi1 * wb0 + xi2 * wc0) * disI;
    acc.y = (xi0 * wa1 + xi1 * wb1 + xi2 * wc1) * disI;
    acc.z = (xi0 * wa2 + xi1 * wb2 + xi2 * wc2) * disI;
    acc.w = (xi0 * wa3 + xi1 * wb3 + xi2 * wc3) * disI;
    for (int j = r0; j < r1; j++) {
        int s = csr_src[j];
        float s0 = x[3 * s + 0], s1 = x[3 * s + 1], s2 = x[3 * s + 2];
        int sr0 = row[s], sr1 = row[s + 1];
        float disS = rsqrtf((float)(sr1 - sr0) + 1.0f);
        acc.x += (s0 * wa0 + s1 * wb0 + s2 * wc0) * disS;
        acc.y += (s0 * wa1 + s1 * wb1 + s2 * wc1) * disS;
        acc.z += (s0 * wa2 + s1 * wb2 + s2 * wc2) * disS;
        acc.w += (s0 * wa3 + s1 * wb3 + s2 * wc3) * disS;
    }
    float4 r;
    r.x = fmaxf(disI * acc.x + b1l[f + 0], 0.0f);
    r.y = fmaxf(disI * acc.y + b1l[f + 1], 0.0f);
    r.z = fmaxf(disI * acc.z + b1l[f + 2], 0.0f);
    r.w = fmaxf(disI * acc.w + b1l[f + 3], 0.0f);
    ((float4*)x1)[i * 8 + fg] = r;
    float ps = r.x * wpl[f + 0] + r.y * wpl[f + 1] + r.z * wpl[f + 2] + r.w * wpl[f + 3];
    float pd = r.x * wpl[32 + f + 0] + r.y * wpl[32 + f + 1] + r.z * wpl[32 + f + 2] + r.w * wpl[32 + f + 3];
#pragma unroll
    for (int o = 4; o; o >>= 1) {
        ps += __shfl_xor(ps, o);
        pd += __shfl_xor(pd, o);
    }
    if (fg == 0) {
        a_src[i] = ps;
        a_dst[i] = pd;
        lab[i] = i;
    }
}

// ---------------- edge selection (block-aggregated compaction) + seed relax ----------------
// Seed relax: posted atomicMins during the selection stream (free vs memory
// time); labels are monotone so this only accelerates LP (starts 1 round ahead).

__global__ void k_select(const int2* __restrict__ edges, const float* __restrict__ a_src,
                         const float* __restrict__ a_dst, const float* __restrict__ bp,
                         long long* __restrict__ seluv, float* __restrict__ selsc,
                         int* __restrict__ selcnt, int* __restrict__ lab, int E) {
    __shared__ int wsum[4];
    __shared__ int sbase;
    int tid = threadIdx.x;
    int e = blockIdx.x * 256 + tid;
    bool sel = false;
    long long pk = 0;
    float score = 0.0f;
    if (e < E) {
        int2 ed = edges[e];
        float z = a_src[ed.x] + a_dst[ed.y] + bp[0];
        score = 1.0f / (1.0f + expf(-z));
        if (score > 0.5f) {
            sel = true;
            pk = ((long long)ed.x << 32) | (u32)ed.y;
            int lu = lab[ed.x], lv = lab[ed.y];
            if (lu < lv) atomicMin(&lab[ed.y], lu);
            else if (lv < lu) atomicMin(&lab[ed.x], lv);
        }
    }
    u64 m = __ballot(sel);
    int wid = tid >> 6, lane = tid & 63;
    if (lane == 0) wsum[wid] = __popcll(m);
    __syncthreads();
    if (tid == 0) {
        int tot = wsum[0] + wsum[1] + wsum[2] + wsum[3];
        sbase = tot ? atomicAdd(selcnt, tot) : 0;
    }
    __syncthreads();
    if (sel) {
        int woff = 0;
        for (int k = 0; k < wid; k++) woff += wsum[k];
        int rank = __popcll(m & ((1ull << lane) - 1ull));
        int pos = sbase + woff + rank;
        seluv[pos] = pk;
        selsc[pos] = score;
    }
}

// ---------------- CC via iterative min-label propagation (R16 structure, deeper jump) ----------------

__global__ void k_lp(const long long* __restrict__ seluv, const int* __restrict__ pcnt,
                     int* __restrict__ lab, int* __restrict__ flags, int t, int N) {
    if (t > 0 && flags[t - 1] == 0) return;
    int n = *pcnt;
    int ch = 0;
    int tid0 = blockIdx.x * blockDim.x + threadIdx.x;
    int stride = gridDim.x * blockDim.x;
    for (int idx = tid0; idx < n; idx += stride) {
        long long pk = seluv[idx];
        int u = (int)(pk >> 32), v = (int)(u32)pk;
        int lu = lab[u], lv = lab[v];
        if (lu < lv) { atomicMin(&lab[v], lu); ch = 1; }
        else if (lv < lu) { atomicMin(&lab[u], lv); ch = 1; }
    }
    // 4-level pointer jump (5 dependent L2 loads, wave-parallel)
    for (int i = tid0; i < N; i += stride) {
        int l = lab[i];
        int m = lab[l];
        m = lab[m];
        m = lab[m];
        m = lab[m];
        if (m < l) { atomicMin(&lab[i], m); ch = 1; }
    }
    if (__ballot(ch) && (int)(threadIdx.x & 63) == 0) flags[t] = 1;
}

// ---------------- component stats (LDS-hash privatized histogram) ----------------

__global__ void k_cnt_ssum(const long long* __restrict__ seluv, const float* __restrict__ selsc,
                           const int* __restrict__ pcnt, const int* __restrict__ lab,
                           float* __restrict__ cnt, float* __restrict__ ssum) {
    __shared__ int hkey[HSLOTS];
    __shared__ float hcnt[HSLOTS];
    __shared__ float hsum[HSLOTS];
    int tid = threadIdx.x;
    for (int k = tid; k < HSLOTS; k += 256) {
        hkey[k] = -1;
        hcnt[k] = 0.0f;
        hsum[k] = 0.0f;
    }
    __syncthreads();
    int n = *pcnt;
    for (int base = blockIdx.x * blockDim.x; base < n; base += gridDim.x * blockDim.x) {
        int idx = base + tid;
        bool valid = idx < n;
        int g = -1;
        float score = 0.0f;
        if (valid) {
            long long pk = seluv[idx];
            int s = (int)(pk >> 32);
            score = selsc[idx];
            g = lab[s];
        }
        u64 m = __ballot(valid);
        while (m) {
            int leader = __ffsll(m) - 1;
            int g0 = __shfl(g, leader);
            bool match = valid && (g == g0);
            float c = match ? 1.0f : 0.0f;
            float sv = match ? score : 0.0f;
#pragma unroll
            for (int o = 32; o; o >>= 1) {
                c += __shfl_xor(c, o);
                sv += __shfl_xor(sv, o);
            }
            if ((int)(tid & 63) == leader) {
                u32 h = ((u32)g0 * 0x9E3779B9u) >> 24;
                bool done = false;
                for (int probe = 0; probe < 16; probe++) {
                    int k = (int)((h + probe) & (HSLOTS - 1));
                    int prev = atomicCAS(&hkey[k], -1, g0);
                    if (prev == -1 || prev == g0) {
                        atomicAdd(&hcnt[k], c);
                        atomicAdd(&hsum[k], sv);
                        done = true;
                        break;
                    }
                }
                if (!done) {
                    atomicAdd(&cnt[g0], c);
                    atomicAdd(&ssum[g0], sv);
                }
            }
            m &= ~__ballot(match);
        }
    }
    __syncthreads();
    for (int k = tid; k < HSLOTS; k += 256) {
        int g = hkey[k];
        if (g >= 0) {
            atomicAdd(&cnt[g], hcnt[k]);
            atomicAdd(&ssum[g], hsum[k]);
        }
    }
}

// load-gated same-address atomicMax (broadcast read; skips once settled)
__global__ void k_findgl(const float* __restrict__ cnt, u64* __restrict__ glpack, int N) {
    int i = blockIdx.x * blockDim.x + threadIdx.x;
    u64 v = 0;
    if (i < N) v = ((u64)__float_as_uint(cnt[i]) << 32) | (u32)i;
#pragma unroll
    for (int o = 32; o; o >>= 1) {
        u64 ov = __shfl_xor(v, o);
        v = v > ov ? v : ov;
    }
    if ((int)(threadIdx.x & 63) == 0) {
        if (*glpack < v) atomicMax(glpack, v);
    }
}

// nx[lab[i]] += x1[i], giant row via LDS per block
__global__ void k_nx_scatter(const float* __restrict__ x1, const int* __restrict__ lab,
                             const u64* __restrict__ glpack, float* __restrict__ nx, int N) {
    __shared__ float ls[HF];
    int tid = threadIdx.x;
    if (tid < HF) ls[tid] = 0.0f;
    __syncthreads();
    int gl = (int)(u32)(*glpack);
    int t = blockIdx.x * blockDim.x + tid;
    int i = t >> 3, fg = t & 7;
    if (i < N) {
        int l = lab[i];
        float4 v = ((const float4*)x1)[i * 8 + fg];
        if (l == gl) {
            atomicAdd(&ls[fg * 4 + 0], v.x);
            atomicAdd(&ls[fg * 4 + 1], v.y);
            atomicAdd(&ls[fg * 4 + 2], v.z);
            atomicAdd(&ls[fg * 4 + 3], v.w);
        } else {
            float* d = &nx[l * HF + fg * 4];
            atomicAdd(d + 0, v.x);
            atomicAdd(d + 1, v.y);
            atomicAdd(d + 2, v.z);
            atomicAdd(d + 3, v.w);
        }
    }
    __syncthreads();
    if (tid < HF) {
        float s = ls[tid];
        if (s != 0.0f) atomicAdd(&nx[gl * HF + tid], s);
    }
}

// ---------------- coarse graph ----------------

__global__ void k_hash_insert(const int2* __restrict__ edges, const int* __restrict__ lab,
                              u64* __restrict__ htab, float* __restrict__ deg3, int E) {
    int e = blockIdx.x * blockDim.x + threadIdx.x;
    if (e >= E) return;
    int2 ed = edges[e];
    int ru = lab[ed.x];
    int rv = lab[ed.y];
    if (ru == rv) return;
    u64 key = ((u64)(u32)ru << 32) | (u32)rv;
    u32 slot = (u32)((key * 0x9E3779B97F4A7C15ull) >> (64 - TBL_BITS));
    bool won = false;
    for (;;) {
        u64 cur = htab[slot];
        if (cur == key) break;
        if (cur == EMPTY_KEY) {
            u64 prev = atomicCAS(&htab[slot], EMPTY_KEY, key);
            if (prev == EMPTY_KEY) { won = true; break; }
            if (prev == key) break;
        }
        slot = (slot + 1) & (TBL_SIZE - 1);
    }
    if (won) atomicAdd(&deg3[rv], 1.0f);
}

// per rep node: cscore, dis3, hs3 = (nx*cscore @ W3) * dis3
__global__ void k_h3(const float* __restrict__ nx, const float* __restrict__ cnt,
                     const float* __restrict__ ssum, const float* __restrict__ deg3,
                     const int* __restrict__ lab, const float* __restrict__ W3,
                     float* __restrict__ hs3, float* __restrict__ dis3, int N) {
    __shared__ float w[HF * HF];
    int tid = threadIdx.x;
    for (int k = tid; k < HF * HF; k += blockDim.x) w[k] = W3[k];
    __syncthreads();
    int i = blockIdx.x * blockDim.x + tid;
    if (i >= N) return;
    if (lab[i] != i) {
        dis3[i] = 0.0f;
        return;
    }
    float cn = cnt[i];
    float c = cn > 0.0f ? ssum[i] / fmaxf(cn, 1.0f) : 1.0f;
    float d3 = 1.0f / sqrtf(deg3[i] + 1.0f);
    dis3[i] = d3;
    float scale = c * d3;
    float r[HF];
#pragma unroll
    for (int f = 0; f < HF; f++) r[f] = 0.0f;
    for (int k = 0; k < HF; k++) {
        float xv = nx[i * HF + k];
#pragma unroll
        for (int f = 0; f < HF; f++) r[f] += xv * w[k * HF + f];
    }
#pragma unroll
    for (int f = 0; f < HF; f++) hs3[i * HF + f] = r[f] * scale;
}

// acc3[b] += hs3[a] for each unique coarse edge (a,b); giant row via LDS
__global__ void k_hash_scatter(const u64* __restrict__ htab, const float* __restrict__ hs3,
                               float* __restrict__ acc3, const u64* __restrict__ glpack) {
    __shared__ float ls[HF];
    int tid = threadIdx.x;
    if (tid < HF) ls[tid] = 0.0f;
    __syncthreads();
    int gl = (int)(u32)(*glpack);
    int t = blockIdx.x * blockDim.x + tid;
    u32 slot = (u32)(t >> 3);
    int fg = t & 7;
    u64 key = htab[slot];
    if (key != EMPTY_KEY) {
        int a = (int)(key >> 32), b = (int)(u32)key;
        float4 v = ((const float4*)hs3)[a * 8 + fg];
        if (b == gl) {
            atomicAdd(&ls[fg * 4 + 0], v.x);
            atomicAdd(&ls[fg * 4 + 1], v.y);
            atomicAdd(&ls[fg * 4 + 2], v.z);
            atomicAdd(&ls[fg * 4 + 3], v.w);
        } else {
            float* d = &acc3[b * HF + fg * 4];
            atomicAdd(d + 0, v.x);
            atomicAdd(d + 1, v.y);
            atomicAdd(d + 2, v.z);
            atomicAdd(d + 3, v.w);
        }
    }
    __syncthreads();
    if (tid < HF) {
        float s = ls[tid];
        if (s != 0.0f) atomicAdd(&acc3[gl * HF + tid], s);
    }
}

// x3 = relu(dis3*(acc3+hs3)+b3) at reps; pool into gs/gc by batch
__global__ void k_final(const float* __restrict__ acc3, const float* __restrict__ hs3,
                        const float* __restrict__ dis3, const int* __restrict__ lab,
                        const int* __restrict__ batch, const float* __restrict__ b3,
                        float* __restrict__ gs, float* __restrict__ gc, int N) {
    int t = blockIdx.x * blockDim.x + threadIdx.x;
    int i = t >> 3, fg = t & 7;
    if (i >= N) return;
    if (lab[i] != i) return;
    float d3 = dis3[i];
    float4 a = ((const float4*)acc3)[i * 8 + fg];
    float4 h = ((const float4*)hs3)[i * 8 + fg];
    int f = fg * 4;
    float4 x3;
    x3.x = fmaxf(d3 * (a.x + h.x) + b3[f + 0], 0.0f);
    x3.y = fmaxf(d3 * (a.y + h.y) + b3[f + 1], 0.0f);
    x3.z = fmaxf(d3 * (a.z + h.z) + b3[f + 2], 0.0f);
    x3.w = fmaxf(d3 * (a.w + h.w) + b3[f + 3], 0.0f);
    int b = batch[i];
    float* g = &gs[b * HF + f];
    atomicAdd(g + 0, x3.x);
    atomicAdd(g + 1, x3.y);
    atomicAdd(g + 2, x3.z);
    atomicAdd(g + 3, x3.w);
    if (fg == 0) atomicAdd(&gc[b], 1.0f);
}

__global__ void k_out(const float* __restrict__ gs, const float* __restrict__ gc,
                      const float* __restrict__ Wf, const float* __restrict__ bf,
                      float* __restrict__ out, int B) {
    int b = threadIdx.x + blockIdx.x * blockDim.x;
    if (b >= B) return;
    float inv = 1.0f / fmaxf(gc[b], 1.0f);
    float z = 0.0f;
#pragma unroll
    for (int f = 0; f < HF; f++) z += gs[b * HF + f] * inv * Wf[f];
    z += bf[0];
    out[b] = 1.0f / (1.0f + expf(-z));
}

// ---------------- host ----------------

static inline size_t align256(size_t x) { return (x + 255) & ~(size_t)255; }

extern "C" void kernel_launch(void* const* d_in, const int* in_sizes, int n_in,
                              void* d_out, int out_size, void* d_ws, size_t ws_size,
                              hipStream_t stream) {
    const float* x = (const float*)d_in[0];
    const int2* edges = (const int2*)d_in[1];
    const int* batch = (const int*)d_in[2];
    const float* W1 = (const float*)d_in[3];
    const float* b1 = (const float*)d_in[4];
    const float* wp = (const float*)d_in[5];
    const float* bp = (const float*)d_in[6];
    const float* W3 = (const float*)d_in[7];
    const float* b3 = (const float*)d_in[8];
    const float* Wf = (const float*)d_in[9];
    const float* bf = (const float*)d_in[10];
    float* outp = (float*)d_out;

    const int N = in_sizes[2];
    const int E = in_sizes[1] / 2;
    const int B = out_size;

    char* p = (char*)d_ws;
    size_t off = 0;
    auto alloc = [&](size_t bytes) -> void* {
        void* r = p + off;
        off = align256(off + bytes);
        return r;
    };
    float* f0 = (float*)alloc((size_t)N * HF * 4);   // nx -> acc3
    float* f1 = (float*)alloc((size_t)N * HF * 4);   // x1 -> hs3
    int* row = (int*)alloc((size_t)(N + 1) * 4);
    int* cursor = (int*)alloc((size_t)N * 4);
    int* bsums = (int*)alloc(4096);
    int* csr_src = (int*)alloc((size_t)E * 4);
    float* a_src = (float*)alloc((size_t)N * 4);
    float* a_dst = (float*)alloc((size_t)N * 4);
    int* lab = (int*)alloc((size_t)N * 4);
    float* cnt = (float*)alloc((size_t)N * 4);
    float* ssum = (float*)alloc((size_t)N * 4);
    float* deg3 = (float*)alloc((size_t)N * 4);
    float* dis3 = (float*)alloc((size_t)N * 4);
    long long* seluv = (long long*)alloc((size_t)E * 8);
    float* selsc = (float*)alloc((size_t)E * 4);
    int* selcnt = (int*)alloc(4);
    int* flags = (int*)alloc(LP_ITERS * 4);
    u64* glpack = (u64*)alloc(8);
    float* gs = (float*)alloc((size_t)B * HF * 4);
    float* gc = (float*)alloc((size_t)B * 4);
    u64* htab = (u64*)alloc((size_t)TBL_SIZE * 8);
    (void)ws_size; (void)n_in;

    const int nb_e = (E + 255) / 256;
    const int nb_n8 = (int)(((size_t)N * 8 + 255) / 256);
    const int nb_n = (N + 255) / 256;
    const int nb_tbl8 = (int)(((size_t)TBL_SIZE * 8) / 256);

    hipMemsetAsync(cursor, 0, (size_t)N * 4, stream);
    hipMemsetAsync(cnt, 0, (size_t)N * 4, stream);
    hipMemsetAsync(ssum, 0, (size_t)N * 4, stream);
    hipMemsetAsync(selcnt, 0, 4, stream);
    hipMemsetAsync(deg3, 0, (size_t)N * 4, stream);
    hipMemsetAsync(flags, 0, LP_ITERS * 4, stream);
    hipMemsetAsync(glpack, 0, 8, stream);
    hipMemsetAsync(gs, 0, (size_t)B * HF * 4, stream);
    hipMemsetAsync(gc, 0, (size_t)B * 4, stream);
    hipMemsetAsync(htab, 0xFF, (size_t)TBL_SIZE * 8, stream);

    // CSR build (sorted by dst); fill is XCD-localized
    k_count<<<nb_e, 256, 0, stream>>>(edges, cursor, E);
    k_scan1<<<nb_n, 256, 0, stream>>>(cursor, row, bsums, N);
    k_scan2<<<1, 1024, 0, stream>>>(bsums, nb_n);
    k_scan3<<<nb_n, 256, 0, stream>>>(row, cursor, bsums, N, E);
    k_fill<<<2048, 256, 0, stream>>>(edges, cursor, csr_src, E, N);

    // GCN1 fused (h1 on the fly); lab init
    k_gather_x1<<<nb_n8, 256, 0, stream>>>(row, csr_src, x, W1, b1, wp, f1, a_src, a_dst, lab, N);

    // CC: select (+seed relax), then gated fused label propagation
    k_select<<<nb_e, 256, 0, stream>>>(edges, a_src, a_dst, bp, seluv, selsc, selcnt, lab, E);
    for (int t = 0; t < LP_ITERS; t++) {
        k_lp<<<2048, 256, 0, stream>>>(seluv, selcnt, lab, flags, t, N);
    }

    // component stats
    k_cnt_ssum<<<1024, 256, 0, stream>>>(seluv, selsc, selcnt, lab, cnt, ssum);
    k_findgl<<<nb_n, 256, 0, stream>>>(cnt, glpack, N);
    hipMemsetAsync(f0, 0, (size_t)N * HF * 4, stream);
    k_nx_scatter<<<nb_n8, 256, 0, stream>>>(f1, lab, glpack, f0, N);

    // coarse graph
    k_hash_insert<<<nb_e, 256, 0, stream>>>(edges, lab, htab, deg3, E);
    k_h3<<<nb_n, 256, 0, stream>>>(f0, cnt, ssum, deg3, lab, W3, f1, dis3, N);
    hipMemsetAsync(f0, 0, (size_t)N * HF * 4, stream);
    k_hash_scatter<<<nb_tbl8, 256, 0, stream>>>(htab, f1, f0, glpack);
    k_final<<<nb_n8, 256, 0, stream>>>(f0, f1, dis3, lab, batch, b3, gs, gc, N);
    k_out<<<1, 128, 0, stream>>>(gs, gc, Wf, bf, outp, B);
}